// Round 11
// baseline (122.265 us; speedup 1.0000x reference)
//
#include <hip/hip_runtime.h>
#include <hip/hip_bf16.h>
#include <math.h>

// B=16, T=1024, C=768, H=128
#define NTOK   16384     // B*T
#define NEMBD  768
#define HDIM   128

typedef __attribute__((ext_vector_type(8)))  short short8;
typedef __attribute__((ext_vector_type(16))) float floatx16;

#define MFMA32(a,b,c) __builtin_amdgcn_mfma_f32_32x32x16_bf16(a,b,c,0,0,0)

__device__ __forceinline__ unsigned short f2bf(float f) {
    unsigned u = __float_as_uint(f);
    u += 0x7fff + ((u >> 16) & 1);          // RNE
    return (unsigned short)(u >> 16);
}
// RNE pack of 2 floats -> 2 bf16 (low = a, high = b).
__device__ __forceinline__ unsigned pack2(float a, float b) {
    __hip_bfloat162 h2 = __float22bfloat162_rn(make_float2(a, b));
    union { __hip_bfloat162 h; unsigned u; } c; c.h = h2;
    return c.u;
}
// truncating bf16 pack: one v_perm_b32. D = [hi16(b) | hi16(a)]
__device__ __forceinline__ unsigned pack2_trunc(float a, float b) {
    return __builtin_amdgcn_perm(__float_as_uint(b), __float_as_uint(a),
                                 0x07060302u);
}

// ---------------------------------------------------------------------------
// Kernel 0: W -> bf16 in MFMA FRAGMENT ORDER. (UNCHANGED from R10.)
// wtf unit (16 B): [(bw*4 + nt)*48 + ksl]*64 + lane holds
// W[k = ksl*16 + (lane>>5)*8 + j][d = nt*32 + (lane&31)].
// ---------------------------------------------------------------------------
__global__ __launch_bounds__(256) void prep_w(
    const float* __restrict__ Wk, const float* __restrict__ Wq,
    const float* __restrict__ Wv, unsigned short* __restrict__ wt)
{
    __shared__ float T[64 * 65];               // [dloc][c], pad 65

    const int tid = threadIdx.x;
    const int bw  = blockIdx.x / 24;
    const int rem = blockIdx.x % 24;
    const int ct  = rem >> 1, dh = rem & 1;
    const int c0  = ct * 64;
    const float* W = (bw == 0) ? Wk : ((bw == 1) ? Wq : Wv);
    const float scale = (bw == 1)
        ? (0.03608439182435161f * 1.4426950408889634f) : 1.0f;

    #pragma unroll
    for (int pass = 0; pass < 4; ++pass) {
        int idx = pass * 256 + tid;            // 0..1023
        int c  = idx >> 4;                     // 0..63
        int d4 = idx & 15;                     // float4 idx within d-half
        float4 v = ((const float4*)W)[(size_t)(c0 + c) * 32 + dh * 16 + d4];
        v.x *= scale; v.y *= scale; v.z *= scale; v.w *= scale;
        T[(d4 * 4 + 0) * 65 + c] = v.x;
        T[(d4 * 4 + 1) * 65 + c] = v.y;
        T[(d4 * 4 + 2) * 65 + c] = v.z;
        T[(d4 * 4 + 3) * 65 + c] = v.w;
    }
    __syncthreads();

    #pragma unroll
    for (int pass = 0; pass < 2; ++pass) {
        int idx  = pass * 256 + tid;           // 0..511
        int dloc = idx >> 3;                   // 0..63
        int c8   = idx & 7;                    // 8-col chunk within c-tile
        const float* row = &T[dloc * 65 + c8 * 8];
        uint4 u = make_uint4(pack2(row[0], row[1]), pack2(row[2], row[3]),
                             pack2(row[4], row[5]), pack2(row[6], row[7]));
        int kc    = ct * 8 + c8;               // global 8-col chunk 0..95
        int ksl   = kc >> 1, hb = kc & 1;
        int dglob = dh * 64 + dloc;
        int nt    = dglob >> 5;
        int lanef = (dglob & 31) + 32 * hb;
        ((uint4*)wt)[(size_t)((bw * 4 + nt) * 48 + ksl) * 64 + lanef] = u;
    }
}

// ---------------------------------------------------------------------------
// Kernel 1: fused x-convert + 3-way GEMM, fragment-order outputs.
// (UNCHANGED from R10 — the 118.8us configuration.)
// ---------------------------------------------------------------------------
__global__ __launch_bounds__(512) void qkv_fused(
    const float* __restrict__ x, const unsigned short* __restrict__ wt,
    unsigned short* __restrict__ kb, unsigned short* __restrict__ qb,
    unsigned short* __restrict__ vT)
{
    __shared__ __align__(16) char As[2][8192];     // 64 rows x 128 B each

    const int tid = threadIdx.x, w = tid >> 6, lane = tid & 63;
    const int l31 = lane & 31, h = lane >> 5;
    const int wm = w >> 2, wn = w & 3;             // 2m x 4n wave grid
    const int l = blockIdx.x;
    const int low3 = l & 7, rest = l >> 3;
    const int mtile = (rest / 3) * 8 + low3;
    const int nh    = rest % 3;
    const int m0 = mtile * 64;
    const int arow = tid >> 3, ac = tid & 7;       // A staging: 8 thr/row

    floatx16 acc;
    #pragma unroll
    for (int i = 0; i < 16; ++i) acc[i] = 0.f;

    const float* asrc = x + (size_t)(m0 + arow) * NEMBD + ac * 8;
    const uint4* wtfb = (const uint4*)wt
                        + (size_t)(nh * 4 + wn) * 48 * 64 + lane;

    // ---- prologue: B(0) frags, pack A(0), x(1) prefetch ----
    uint4 bq[2][4];
    #pragma unroll
    for (int ks = 0; ks < 4; ++ks) bq[0][ks] = wtfb[ks * 64];
    float4 a0 = ((const float4*)asrc)[0];
    float4 a1 = ((const float4*)asrc)[1];
    {
        uint4 u0 = make_uint4(pack2(a0.x, a0.y), pack2(a0.z, a0.w),
                              pack2(a1.x, a1.y), pack2(a1.z, a1.w));
        *(uint4*)(As[0] + arow * 128 + ((ac ^ (arow & 7)) * 16)) = u0;
    }
    {
        const float4* src = (const float4*)(asrc + 64);
        a0 = src[0]; a1 = src[1];               // x(1), stays in flight
    }
    asm volatile("s_waitcnt lgkmcnt(0)" ::: "memory");
    __builtin_amdgcn_sched_barrier(0);
    __builtin_amdgcn_s_barrier();

    #pragma unroll
    for (int it = 0; it < 12; ++it) {
        char* Acur = As[it & 1];
        char* Anxt = As[(it & 1) ^ 1];

        if (it < 11) {
            #pragma unroll
            for (int ks = 0; ks < 4; ++ks)
                bq[(it + 1) & 1][ks] = wtfb[((it + 1) * 4 + ks) * 64];
            uint4 u0 = make_uint4(pack2(a0.x, a0.y), pack2(a0.z, a0.w),
                                  pack2(a1.x, a1.y), pack2(a1.z, a1.w));
            *(uint4*)(Anxt + arow * 128 + ((ac ^ (arow & 7)) * 16)) = u0;
            if (it < 10) {
                const float4* src = (const float4*)(asrc + (it + 2) * 64);
                a0 = src[0]; a1 = src[1];
            }
        }

        // ---- MFMA: kb/qb swapped operands (acc = C^T), vT unswapped ----
        const int ar = wm * 32 + l31;
        #pragma unroll
        for (int ks = 0; ks < 4; ++ks) {
            short8 af = *(const short8*)(Acur + ar * 128
                                         + (((2 * ks + h) ^ (ar & 7)) * 16));
            union { uint4 q; short8 v; } bb; bb.q = bq[it & 1][ks];
            if (nh < 2) acc = MFMA32(bb.v, af, acc);
            else        acc = MFMA32(af, bb.v, acc);
        }

        if (it < 11) {
            asm volatile("s_waitcnt lgkmcnt(0)" ::: "memory");
            __builtin_amdgcn_sched_barrier(0);
            __builtin_amdgcn_s_barrier();
        }
    }

    // ---- epilogue: pairs + cross-half swap -> 2 coalesced 16B stores ----
    const int bidx = m0 >> 10;
    const int ktl  = ((m0 & 1023) >> 5) + wm;      // t-tile within batch
    unsigned own[8];
    #pragma unroll
    for (int i = 0; i < 8; ++i) own[i] = pack2(acc[2*i], acc[2*i+1]);
    asm("v_permlane32_swap_b32 %0, %1" : "+v"(own[0]), "+v"(own[2]));
    asm("v_permlane32_swap_b32 %0, %1" : "+v"(own[1]), "+v"(own[3]));
    asm("v_permlane32_swap_b32 %0, %1" : "+v"(own[4]), "+v"(own[6]));
    asm("v_permlane32_swap_b32 %0, %1" : "+v"(own[5]), "+v"(own[7]));
    uint4 u1 = make_uint4(own[0], own[1], own[2], own[3]);
    uint4 u2 = make_uint4(own[4], own[5], own[6], own[7]);
    if (nh < 2) {
        uint4* outp = (uint4*)((nh == 0) ? kb : qb);
        size_t base = ((size_t)(bidx * 32 + ktl) * 8 + 2 * wn) * 64 + lane;
        outp[base]      = u1;      // ks = 2wn
        outp[base + 64] = u2;      // ks = 2wn+1
    } else {
        uint4* outp = (uint4*)vT;
        size_t base = ((size_t)(bidx * 32 + ktl) * 4 + wn) * 2 * 64 + lane;
        outp[base]      = u1;      // q = 0 (t-offs 0..15)
        outp[base + 64] = u2;      // q = 1 (t-offs 16..31)
    }
}

// ---------------------------------------------------------------------------
// Kernel 2: flash attention, fragment-order loads (R10 form) + LONGEST-
// JOB-FIRST block remap. R10 order dispatched all 256 light blocks
// (qt 0..15) first and all heavy (qt 16..31) last -> worst makespan at
// 2 blocks/CU. New map: j = blockIdx>>4 gives dispatch order
// qt = 31, 0, 30, 1, ... (heavy first, heavy+light co-resident per CU).
// Pure index permutation: same blocks, bit-identical output.
// ---------------------------------------------------------------------------
__global__ __launch_bounds__(256) void attn_mfma(
    const unsigned short* __restrict__ qb, const unsigned short* __restrict__ kb,
    const unsigned short* __restrict__ vT, float* __restrict__ out)
{
    __shared__ __align__(16) float Obuf[4 * 32 * 128];   // 64 KB, per-wave
    __shared__ float lred[128];

    const int tid = threadIdx.x, w = tid >> 6, lane = tid & 63;
    const int l31 = lane & 31, h = lane >> 5;
    const int j  = blockIdx.x >> 4;          // 0..31, dispatch-ordered
    const int b  = blockIdx.x & 15;
    const int qt = (j & 1) ? (j >> 1) : (31 - (j >> 1));

    // fragment-unit pointers (uint4 = 16 B unit), 16384 units per batch
    const uint4* qbu = (const uint4*)qb + (size_t)b * 16384 + lane;
    const uint4* kbu = (const uint4*)kb + (size_t)b * 16384 + lane;
    const uint4* vtu = (const uint4*)vT + (size_t)b * 16384 + lane;

    short8 qf[8];
    #pragma unroll
    for (int ks = 0; ks < 8; ++ks)
        qf[ks] = *(const short8*)(qbu + ((size_t)qt * 8 + ks) * 64);

    floatx16 o[4];
    #pragma unroll
    for (int nt = 0; nt < 4; ++nt)
        #pragma unroll
        for (int i = 0; i < 16; ++i) o[nt][i] = 0.f;
    float l_r = 0.f;

    short8 kf[8];
    if (w <= qt) {
        #pragma unroll
        for (int ks = 0; ks < 8; ++ks)
            kf[ks] = *(const short8*)(kbu + ((size_t)w * 8 + ks) * 64);
    }

    for (int st = w; st <= qt; st += 4) {
        // ---- V loads first (independent of S chain), coalesced ----
        short8 vf[8];
        #pragma unroll
        for (int nt = 0; nt < 4; ++nt) {
            vf[nt * 2 + 0] = *(const short8*)(vtu + (((size_t)st * 4 + nt) * 2 + 0) * 64);
            vf[nt * 2 + 1] = *(const short8*)(vtu + (((size_t)st * 4 + nt) * 2 + 1) * 64);
        }
        // ---- S^T = K * Q^T  (log2e already in Q) ----
        floatx16 s;
        #pragma unroll
        for (int i = 0; i < 16; ++i) s[i] = 0.f;
        __builtin_amdgcn_s_setprio(1);
        #pragma unroll
        for (int ks = 0; ks < 8; ++ks) s = MFMA32(kf[ks], qf[ks], s);
        __builtin_amdgcn_s_setprio(0);

        // ---- prefetch next K tile (coalesced) ----
        if (st + 4 <= qt) {
            #pragma unroll
            for (int ks = 0; ks < 8; ++ks)
                kf[ks] = *(const short8*)(kbu + ((size_t)(st + 4) * 8 + ks) * 64);
        }

        if (st == qt) {            // causal mask on diagonal tile
            #pragma unroll
            for (int r = 0; r < 16; ++r) {
                int key = (r & 3) + 8 * (r >> 2) + 4 * h;
                if (key > l31) s[r] = -1e30f;
            }
        }
        // ---- softmax numerator, fixed m=0: p = 2^s ----
        float p16[16];
        float ps0 = 0.f, ps1 = 0.f, ps2 = 0.f, ps3 = 0.f;
        #pragma unroll
        for (int r = 0; r < 4; ++r) {
            p16[4*r+0] = __builtin_amdgcn_exp2f(s[4*r+0]);
            p16[4*r+1] = __builtin_amdgcn_exp2f(s[4*r+1]);
            p16[4*r+2] = __builtin_amdgcn_exp2f(s[4*r+2]);
            p16[4*r+3] = __builtin_amdgcn_exp2f(s[4*r+3]);
            ps0 += p16[4*r+0]; ps1 += p16[4*r+1];
            ps2 += p16[4*r+2]; ps3 += p16[4*r+3];
        }
        l_r += (ps0 + ps1) + (ps2 + ps3);

        // ---- P^T -> B-operand frags via row-swap ----
        unsigned own[8];
        #pragma unroll
        for (int i = 0; i < 8; ++i) own[i] = pack2_trunc(p16[2*i], p16[2*i+1]);
        asm("v_permlane32_swap_b32 %0, %1" : "+v"(own[0]), "+v"(own[2]));
        asm("v_permlane32_swap_b32 %0, %1" : "+v"(own[1]), "+v"(own[3]));
        asm("v_permlane32_swap_b32 %0, %1" : "+v"(own[4]), "+v"(own[6]));
        asm("v_permlane32_swap_b32 %0, %1" : "+v"(own[5]), "+v"(own[7]));
        short8 pf[2];
        {
            union { short8 v; unsigned uu[4]; } f0, f1;
            f0.uu[0]=own[0]; f0.uu[1]=own[1]; f0.uu[2]=own[2]; f0.uu[3]=own[3];
            f1.uu[0]=own[4]; f1.uu[1]=own[5]; f1.uu[2]=own[6]; f1.uu[3]=own[7];
            pf[0] = f0.v; pf[1] = f1.v;
        }
        // ---- O^T += V^T * P^T ----
        __builtin_amdgcn_s_setprio(1);
        #pragma unroll
        for (int nt = 0; nt < 4; ++nt) {
            o[nt] = MFMA32(vf[nt * 2 + 0], pf[0], o[nt]);
            o[nt] = MFMA32(vf[nt * 2 + 1], pf[1], o[nt]);
        }
        __builtin_amdgcn_s_setprio(0);
    }

    // ---- merge: each wave -> private buffer, ONE barrier, parallel sum ----
    l_r += __shfl_xor(l_r, 32, 64);
    if (lane < 32) lred[w * 32 + l31] = l_r;
    {
        float* mybuf = &Obuf[w * 4096];
        #pragma unroll
        for (int nt = 0; nt < 4; ++nt) {
            #pragma unroll
            for (int g = 0; g < 4; ++g) {
                int chunk = nt * 8 + 2 * g + h;
                int slot  = (chunk & 24) | ((chunk & 7) ^ (l31 & 7));
                *((float4*)&mybuf[l31 * 128] + slot) =
                    make_float4(o[nt][4*g+0], o[nt][4*g+1],
                                o[nt][4*g+2], o[nt][4*g+3]);
            }
        }
    }
    __syncthreads();
    {
        int q  = tid >> 3;
        int cb = (tid & 7) * 4;
        float inv = 1.f / (lred[q] + lred[32 + q] + lred[64 + q] + lred[96 + q]);
        #pragma unroll
        for (int cc = 0; cc < 4; ++cc) {
            int chunk = cb + cc;
            int slot  = (chunk & 24) | ((chunk & 7) ^ (q & 7));
            float4 v0 = *((float4*)&Obuf[0 * 4096 + q * 128] + slot);
            float4 v1 = *((float4*)&Obuf[1 * 4096 + q * 128] + slot);
            float4 v2 = *((float4*)&Obuf[2 * 4096 + q * 128] + slot);
            float4 v3 = *((float4*)&Obuf[3 * 4096 + q * 128] + slot);
            float4 v = make_float4((v0.x + v1.x + v2.x + v3.x) * inv,
                                   (v0.y + v1.y + v2.y + v3.y) * inv,
                                   (v0.z + v1.z + v2.z + v3.z) * inv,
                                   (v0.w + v1.w + v2.w + v3.w) * inv);
            *(float4*)&out[((size_t)(b * 1024 + qt * 32 + q)) * HDIM + chunk * 4] = v;
        }
    }
}

// ---------------------------------------------------------------------------
extern "C" void kernel_launch(void* const* d_in, const int* in_sizes, int n_in,
                              void* d_out, int out_size, void* d_ws, size_t ws_size,
                              hipStream_t stream)
{
    const float* x  = (const float*)d_in[0];
    const float* Wk = (const float*)d_in[1];
    const float* Wq = (const float*)d_in[2];
    const float* Wv = (const float*)d_in[3];
    float* outp = (float*)d_out;

    char* ws = (char*)d_ws;
    unsigned short* wt = (unsigned short*)(ws);               //  589824 B
    unsigned short* kb = (unsigned short*)(ws + 589824);      // 4194304 B
    unsigned short* qb = (unsigned short*)(ws + 4784128);     // 4194304 B
    unsigned short* vT = (unsigned short*)(ws + 8978432);     // 4194304 B

    prep_w<<<72, 256, 0, stream>>>(Wk, Wq, Wv, wt);
    qkv_fused<<<768, 512, 0, stream>>>(x, wt, kb, qb, vT);
    attn_mfma<<<512, 256, 0, stream>>>(qb, kb, vT, outp);
}

// Round 12
// 119.071 us; speedup vs baseline: 1.0268x; 1.0268x over previous
//
#include <hip/hip_runtime.h>
#include <hip/hip_bf16.h>
#include <math.h>

// B=16, T=1024, C=768, H=128
#define NTOK   16384     // B*T
#define NEMBD  768
#define HDIM   128

typedef __attribute__((ext_vector_type(8)))  short short8;
typedef __attribute__((ext_vector_type(16))) float floatx16;

#define MFMA32(a,b,c) __builtin_amdgcn_mfma_f32_32x32x16_bf16(a,b,c,0,0,0)

__device__ __forceinline__ unsigned short f2bf(float f) {
    unsigned u = __float_as_uint(f);
    u += 0x7fff + ((u >> 16) & 1);          // RNE
    return (unsigned short)(u >> 16);
}
// RNE pack of 2 floats -> 2 bf16 (low = a, high = b).
__device__ __forceinline__ unsigned pack2(float a, float b) {
    __hip_bfloat162 h2 = __float22bfloat162_rn(make_float2(a, b));
    union { __hip_bfloat162 h; unsigned u; } c; c.h = h2;
    return c.u;
}
// truncating bf16 pack: one v_perm_b32. D = [hi16(b) | hi16(a)]
__device__ __forceinline__ unsigned pack2_trunc(float a, float b) {
    return __builtin_amdgcn_perm(__float_as_uint(b), __float_as_uint(a),
                                 0x07060302u);
}

// ---------------------------------------------------------------------------
// Kernel 0: W -> bf16 in MFMA FRAGMENT ORDER. (UNCHANGED from R10.)
// wtf unit (16 B): [(bw*4 + nt)*48 + ksl]*64 + lane holds
// W[k = ksl*16 + (lane>>5)*8 + j][d = nt*32 + (lane&31)].
// ---------------------------------------------------------------------------
__global__ __launch_bounds__(256) void prep_w(
    const float* __restrict__ Wk, const float* __restrict__ Wq,
    const float* __restrict__ Wv, unsigned short* __restrict__ wt)
{
    __shared__ float T[64 * 65];               // [dloc][c], pad 65

    const int tid = threadIdx.x;
    const int bw  = blockIdx.x / 24;
    const int rem = blockIdx.x % 24;
    const int ct  = rem >> 1, dh = rem & 1;
    const int c0  = ct * 64;
    const float* W = (bw == 0) ? Wk : ((bw == 1) ? Wq : Wv);
    const float scale = (bw == 1)
        ? (0.03608439182435161f * 1.4426950408889634f) : 1.0f;

    #pragma unroll
    for (int pass = 0; pass < 4; ++pass) {
        int idx = pass * 256 + tid;            // 0..1023
        int c  = idx >> 4;                     // 0..63
        int d4 = idx & 15;                     // float4 idx within d-half
        float4 v = ((const float4*)W)[(size_t)(c0 + c) * 32 + dh * 16 + d4];
        v.x *= scale; v.y *= scale; v.z *= scale; v.w *= scale;
        T[(d4 * 4 + 0) * 65 + c] = v.x;
        T[(d4 * 4 + 1) * 65 + c] = v.y;
        T[(d4 * 4 + 2) * 65 + c] = v.z;
        T[(d4 * 4 + 3) * 65 + c] = v.w;
    }
    __syncthreads();

    #pragma unroll
    for (int pass = 0; pass < 2; ++pass) {
        int idx  = pass * 256 + tid;           // 0..511
        int dloc = idx >> 3;                   // 0..63
        int c8   = idx & 7;                    // 8-col chunk within c-tile
        const float* row = &T[dloc * 65 + c8 * 8];
        uint4 u = make_uint4(pack2(row[0], row[1]), pack2(row[2], row[3]),
                             pack2(row[4], row[5]), pack2(row[6], row[7]));
        int kc    = ct * 8 + c8;               // global 8-col chunk 0..95
        int ksl   = kc >> 1, hb = kc & 1;
        int dglob = dh * 64 + dloc;
        int nt    = dglob >> 5;
        int lanef = (dglob & 31) + 32 * hb;
        ((uint4*)wt)[(size_t)((bw * 4 + nt) * 48 + ksl) * 64 + lanef] = u;
    }
}

// ---------------------------------------------------------------------------
// Kernel 1: fused x-convert + 3-way GEMM, fragment-order outputs, 4-WAVE
// blocks with wave-tile 64m x 32n (2 m-accumulators per wave).
// R8 measurement: qkv warm == cold (19us) => not HBM-cold-bound; dominant
// term is B-fragment L2 traffic (each wave re-reads 4KB/iter; 294 MB total
// ~ 8.4us at L2 ceiling). Each B-frag now feeds 8 MFMAs (2 m-subtiles)
// instead of 4 -> B L2 traffic halves to 147 MB; MFMA density doubles.
// Block 256 thr, grid 768 (256 m-tiles x 3 matrices, XCD-sibling swizzle),
// LDS 16 KB A-dbuf, barrier = lgkmcnt(0) only (VMEM stays in flight).
// ---------------------------------------------------------------------------
__global__ __launch_bounds__(256) void qkv_fused(
    const float* __restrict__ x, const unsigned short* __restrict__ wt,
    unsigned short* __restrict__ kb, unsigned short* __restrict__ qb,
    unsigned short* __restrict__ vT)
{
    __shared__ __align__(16) char As[2][8192];     // 64 rows x 128 B each

    const int tid = threadIdx.x, wn = tid >> 6, lane = tid & 63;
    const int l31 = lane & 31, h = lane >> 5;
    const int l = blockIdx.x;
    const int low3 = l & 7, rest = l >> 3;
    const int mtile = (rest / 3) * 8 + low3;
    const int nh    = rest % 3;
    const int m0 = mtile * 64;
    const int arow = tid >> 2, ac = tid & 3;       // A staging: 4 thr/row

    floatx16 acc0, acc1;
    #pragma unroll
    for (int i = 0; i < 16; ++i) { acc0[i] = 0.f; acc1[i] = 0.f; }

    const float* asrc = x + (size_t)(m0 + arow) * NEMBD + ac * 16;
    const uint4* wtfb = (const uint4*)wt
                        + (size_t)(nh * 4 + wn) * 48 * 64 + lane;

    // ---- prologue: B(0) frags, pack A(0), x(1) prefetch ----
    uint4 bq[2][4];
    #pragma unroll
    for (int ks = 0; ks < 4; ++ks) bq[0][ks] = wtfb[ks * 64];
    float4 a0 = ((const float4*)asrc)[0];
    float4 a1 = ((const float4*)asrc)[1];
    float4 a2 = ((const float4*)asrc)[2];
    float4 a3 = ((const float4*)asrc)[3];
    {
        uint4 u0 = make_uint4(pack2(a0.x, a0.y), pack2(a0.z, a0.w),
                              pack2(a1.x, a1.y), pack2(a1.z, a1.w));
        uint4 u1 = make_uint4(pack2(a2.x, a2.y), pack2(a2.z, a2.w),
                              pack2(a3.x, a3.y), pack2(a3.z, a3.w));
        int cA = 2 * ac, cB = 2 * ac + 1;
        *(uint4*)(As[0] + arow * 128 + ((cA ^ (arow & 7)) * 16)) = u0;
        *(uint4*)(As[0] + arow * 128 + ((cB ^ (arow & 7)) * 16)) = u1;
    }
    {
        const float4* src = (const float4*)(asrc + 64);
        a0 = src[0]; a1 = src[1]; a2 = src[2]; a3 = src[3];
    }
    asm volatile("s_waitcnt lgkmcnt(0)" ::: "memory");
    __builtin_amdgcn_sched_barrier(0);
    __builtin_amdgcn_s_barrier();

    #pragma unroll
    for (int it = 0; it < 12; ++it) {
        char* Acur = As[it & 1];
        char* Anxt = As[(it & 1) ^ 1];

        if (it < 11) {
            // ---- prefetch B(it+1) frags (consumed next iter) ----
            #pragma unroll
            for (int ks = 0; ks < 4; ++ks)
                bq[(it + 1) & 1][ks] = wtfb[((it + 1) * 4 + ks) * 64];
            // ---- pack A(it+1) (auto-waits x(it+1), keeps B in flight) ----
            uint4 u0 = make_uint4(pack2(a0.x, a0.y), pack2(a0.z, a0.w),
                                  pack2(a1.x, a1.y), pack2(a1.z, a1.w));
            uint4 u1 = make_uint4(pack2(a2.x, a2.y), pack2(a2.z, a2.w),
                                  pack2(a3.x, a3.y), pack2(a3.z, a3.w));
            int cA = 2 * ac, cB = 2 * ac + 1;
            *(uint4*)(Anxt + arow * 128 + ((cA ^ (arow & 7)) * 16)) = u0;
            *(uint4*)(Anxt + arow * 128 + ((cB ^ (arow & 7)) * 16)) = u1;
            if (it < 10) {
                const float4* src = (const float4*)(asrc + (it + 2) * 64);
                a0 = src[0]; a1 = src[1]; a2 = src[2]; a3 = src[3];
            }
        }

        // ---- MFMA: 4 ks x 2 m-subtiles, B-frag reused across both ----
        const int ar0 = l31, ar1 = 32 + l31;
        #pragma unroll
        for (int ks = 0; ks < 4; ++ks) {
            short8 af0 = *(const short8*)(Acur + ar0 * 128
                                          + (((2 * ks + h) ^ (ar0 & 7)) * 16));
            short8 af1 = *(const short8*)(Acur + ar1 * 128
                                          + (((2 * ks + h) ^ (ar1 & 7)) * 16));
            union { uint4 q; short8 v; } bb; bb.q = bq[it & 1][ks];
            if (nh < 2) {
                acc0 = MFMA32(bb.v, af0, acc0);
                acc1 = MFMA32(bb.v, af1, acc1);
            } else {
                acc0 = MFMA32(af0, bb.v, acc0);
                acc1 = MFMA32(af1, bb.v, acc1);
            }
        }

        if (it < 11) {
            asm volatile("s_waitcnt lgkmcnt(0)" ::: "memory");
            __builtin_amdgcn_sched_barrier(0);
            __builtin_amdgcn_s_barrier();
        }
    }

    // ---- epilogue: two m-subtiles, pairs + swap -> coalesced stores ----
    const int bidx = m0 >> 10;
    const int kt0  = (m0 & 1023) >> 5;             // t-tile within batch
    #pragma unroll
    for (int msub = 0; msub < 2; ++msub) {
        const floatx16& acc = msub ? acc1 : acc0;
        unsigned own[8];
        #pragma unroll
        for (int i = 0; i < 8; ++i) own[i] = pack2(acc[2*i], acc[2*i+1]);
        asm("v_permlane32_swap_b32 %0, %1" : "+v"(own[0]), "+v"(own[2]));
        asm("v_permlane32_swap_b32 %0, %1" : "+v"(own[1]), "+v"(own[3]));
        asm("v_permlane32_swap_b32 %0, %1" : "+v"(own[4]), "+v"(own[6]));
        asm("v_permlane32_swap_b32 %0, %1" : "+v"(own[5]), "+v"(own[7]));
        uint4 u1 = make_uint4(own[0], own[1], own[2], own[3]);
        uint4 u2 = make_uint4(own[4], own[5], own[6], own[7]);
        const int ktl = kt0 + msub;
        if (nh < 2) {
            uint4* outp = (uint4*)((nh == 0) ? kb : qb);
            size_t base = ((size_t)(bidx * 32 + ktl) * 8 + 2 * wn) * 64 + lane;
            outp[base]      = u1;      // ks = 2wn
            outp[base + 64] = u2;      // ks = 2wn+1
        } else {
            uint4* outp = (uint4*)vT;
            size_t base = ((size_t)(bidx * 32 + ktl) * 4 + wn) * 2 * 64 + lane;
            outp[base]      = u1;      // q = 0 (t-offs 0..15)
            outp[base + 64] = u2;      // q = 1 (t-offs 16..31)
        }
    }
}

// ---------------------------------------------------------------------------
// Kernel 2: flash attention, fragment-order loads. (EXACT R10 form — the
// 118.8us configuration; R11's LJF remap reverted, neutral-to-negative.)
// ---------------------------------------------------------------------------
__global__ __launch_bounds__(256) void attn_mfma(
    const unsigned short* __restrict__ qb, const unsigned short* __restrict__ kb,
    const unsigned short* __restrict__ vT, float* __restrict__ out)
{
    __shared__ __align__(16) float Obuf[4 * 32 * 128];   // 64 KB, per-wave
    __shared__ float lred[128];

    const int tid = threadIdx.x, w = tid >> 6, lane = tid & 63;
    const int l31 = lane & 31, h = lane >> 5;
    const int u  = blockIdx.x & 255;
    const int b  = u & 15, p = u >> 4;
    const int qt = (blockIdx.x >> 8) ? (31 - p) : p;

    // fragment-unit pointers (uint4 = 16 B unit), 16384 units per batch
    const uint4* qbu = (const uint4*)qb + (size_t)b * 16384 + lane;
    const uint4* kbu = (const uint4*)kb + (size_t)b * 16384 + lane;
    const uint4* vtu = (const uint4*)vT + (size_t)b * 16384 + lane;

    short8 qf[8];
    #pragma unroll
    for (int ks = 0; ks < 8; ++ks)
        qf[ks] = *(const short8*)(qbu + ((size_t)qt * 8 + ks) * 64);

    floatx16 o[4];
    #pragma unroll
    for (int nt = 0; nt < 4; ++nt)
        #pragma unroll
        for (int i = 0; i < 16; ++i) o[nt][i] = 0.f;
    float l_r = 0.f;

    short8 kf[8];
    if (w <= qt) {
        #pragma unroll
        for (int ks = 0; ks < 8; ++ks)
            kf[ks] = *(const short8*)(kbu + ((size_t)w * 8 + ks) * 64);
    }

    for (int st = w; st <= qt; st += 4) {
        // ---- V loads first (independent of S chain), coalesced ----
        short8 vf[8];
        #pragma unroll
        for (int nt = 0; nt < 4; ++nt) {
            vf[nt * 2 + 0] = *(const short8*)(vtu + (((size_t)st * 4 + nt) * 2 + 0) * 64);
            vf[nt * 2 + 1] = *(const short8*)(vtu + (((size_t)st * 4 + nt) * 2 + 1) * 64);
        }
        // ---- S^T = K * Q^T  (log2e already in Q) ----
        floatx16 s;
        #pragma unroll
        for (int i = 0; i < 16; ++i) s[i] = 0.f;
        __builtin_amdgcn_s_setprio(1);
        #pragma unroll
        for (int ks = 0; ks < 8; ++ks) s = MFMA32(kf[ks], qf[ks], s);
        __builtin_amdgcn_s_setprio(0);

        // ---- prefetch next K tile (coalesced) ----
        if (st + 4 <= qt) {
            #pragma unroll
            for (int ks = 0; ks < 8; ++ks)
                kf[ks] = *(const short8*)(kbu + ((size_t)(st + 4) * 8 + ks) * 64);
        }

        if (st == qt) {            // causal mask on diagonal tile
            #pragma unroll
            for (int r = 0; r < 16; ++r) {
                int key = (r & 3) + 8 * (r >> 2) + 4 * h;
                if (key > l31) s[r] = -1e30f;
            }
        }
        // ---- softmax numerator, fixed m=0: p = 2^s ----
        float p16[16];
        float ps0 = 0.f, ps1 = 0.f, ps2 = 0.f, ps3 = 0.f;
        #pragma unroll
        for (int r = 0; r < 4; ++r) {
            p16[4*r+0] = __builtin_amdgcn_exp2f(s[4*r+0]);
            p16[4*r+1] = __builtin_amdgcn_exp2f(s[4*r+1]);
            p16[4*r+2] = __builtin_amdgcn_exp2f(s[4*r+2]);
            p16[4*r+3] = __builtin_amdgcn_exp2f(s[4*r+3]);
            ps0 += p16[4*r+0]; ps1 += p16[4*r+1];
            ps2 += p16[4*r+2]; ps3 += p16[4*r+3];
        }
        l_r += (ps0 + ps1) + (ps2 + ps3);

        // ---- P^T -> B-operand frags via row-swap ----
        unsigned own[8];
        #pragma unroll
        for (int i = 0; i < 8; ++i) own[i] = pack2_trunc(p16[2*i], p16[2*i+1]);
        asm("v_permlane32_swap_b32 %0, %1" : "+v"(own[0]), "+v"(own[2]));
        asm("v_permlane32_swap_b32 %0, %1" : "+v"(own[1]), "+v"(own[3]));
        asm("v_permlane32_swap_b32 %0, %1" : "+v"(own[4]), "+v"(own[6]));
        asm("v_permlane32_swap_b32 %0, %1" : "+v"(own[5]), "+v"(own[7]));
        short8 pf[2];
        {
            union { short8 v; unsigned uu[4]; } f0, f1;
            f0.uu[0]=own[0]; f0.uu[1]=own[1]; f0.uu[2]=own[2]; f0.uu[3]=own[3];
            f1.uu[0]=own[4]; f1.uu[1]=own[5]; f1.uu[2]=own[6]; f1.uu[3]=own[7];
            pf[0] = f0.v; pf[1] = f1.v;
        }
        // ---- O^T += V^T * P^T ----
        __builtin_amdgcn_s_setprio(1);
        #pragma unroll
        for (int nt = 0; nt < 4; ++nt) {
            o[nt] = MFMA32(vf[nt * 2 + 0], pf[0], o[nt]);
            o[nt] = MFMA32(vf[nt * 2 + 1], pf[1], o[nt]);
        }
        __builtin_amdgcn_s_setprio(0);
    }

    // ---- merge: each wave -> private buffer, ONE barrier, parallel sum ----
    l_r += __shfl_xor(l_r, 32, 64);
    if (lane < 32) lred[w * 32 + l31] = l_r;
    {
        float* mybuf = &Obuf[w * 4096];
        #pragma unroll
        for (int nt = 0; nt < 4; ++nt) {
            #pragma unroll
            for (int g = 0; g < 4; ++g) {
                int chunk = nt * 8 + 2 * g + h;
                int slot  = (chunk & 24) | ((chunk & 7) ^ (l31 & 7));
                *((float4*)&mybuf[l31 * 128] + slot) =
                    make_float4(o[nt][4*g+0], o[nt][4*g+1],
                                o[nt][4*g+2], o[nt][4*g+3]);
            }
        }
    }
    __syncthreads();
    {
        int q  = tid >> 3;
        int cb = (tid & 7) * 4;
        float inv = 1.f / (lred[q] + lred[32 + q] + lred[64 + q] + lred[96 + q]);
        #pragma unroll
        for (int cc = 0; cc < 4; ++cc) {
            int chunk = cb + cc;
            int slot  = (chunk & 24) | ((chunk & 7) ^ (q & 7));
            float4 v0 = *((float4*)&Obuf[0 * 4096 + q * 128] + slot);
            float4 v1 = *((float4*)&Obuf[1 * 4096 + q * 128] + slot);
            float4 v2 = *((float4*)&Obuf[2 * 4096 + q * 128] + slot);
            float4 v3 = *((float4*)&Obuf[3 * 4096 + q * 128] + slot);
            float4 v = make_float4((v0.x + v1.x + v2.x + v3.x) * inv,
                                   (v0.y + v1.y + v2.y + v3.y) * inv,
                                   (v0.z + v1.z + v2.z + v3.z) * inv,
                                   (v0.w + v1.w + v2.w + v3.w) * inv);
            *(float4*)&out[((size_t)(b * 1024 + qt * 32 + q)) * HDIM + chunk * 4] = v;
        }
    }
}

// ---------------------------------------------------------------------------
extern "C" void kernel_launch(void* const* d_in, const int* in_sizes, int n_in,
                              void* d_out, int out_size, void* d_ws, size_t ws_size,
                              hipStream_t stream)
{
    const float* x  = (const float*)d_in[0];
    const float* Wk = (const float*)d_in[1];
    const float* Wq = (const float*)d_in[2];
    const float* Wv = (const float*)d_in[3];
    float* outp = (float*)d_out;

    char* ws = (char*)d_ws;
    unsigned short* wt = (unsigned short*)(ws);               //  589824 B
    unsigned short* kb = (unsigned short*)(ws + 589824);      // 4194304 B
    unsigned short* qb = (unsigned short*)(ws + 4784128);     // 4194304 B
    unsigned short* vT = (unsigned short*)(ws + 8978432);     // 4194304 B

    prep_w<<<72, 256, 0, stream>>>(Wk, Wq, Wv, wt);
    qkv_fused<<<768, 256, 0, stream>>>(x, wt, kb, qb, vT);
    attn_mfma<<<512, 256, 0, stream>>>(qb, kb, vT, outp);
}